// Round 16
// baseline (280.161 us; speedup 1.0000x reference)
//
#include <hip/hip_runtime.h>
#include <hip/hip_bf16.h>
#include <math.h>

// N=25000, E=400000, S=8, NB=8, RMAX=5, EMB=16, MULS=(8,4,4), DIMS=(1,3,5), WNUM=1024
// g[e,u] = sum_p c[e,p] * ( sum_k h3[e,k] gw4[k, col(p,u)] + gb4[col(p,u)] )
// out[a, f(u,m)] = (1/cnt[a]) * sum_{e: dst=a} alpha * g[e,u] * sh[e, m]
//
// r16 = r15 (3-node col-major pipeline) + edge_fused processes TWO tiles per
// one-wave WG SEQUENTIALLY (#pragma unroll 1 — per-wave code/registers are
// bit-identical to r15, only WG count halves). Clean test of per-WG fixed
// overhead (dispatch + s_load prologue), which r7 confounded with 2x registers.

typedef __attribute__((ext_vector_type(8))) short short8;
typedef __attribute__((ext_vector_type(4))) float f32x4;

#define EROW 28    // CSR row stride (floats): g[16]+sh[9]+pad
#define EROWC 32   // col-major row stride (floats): 128 B = 2 cache lines
#define MAXD 48    // col-major slots/atom; P(Poisson(16) >= 48) ~ 5e-12/atom
#define MAXT 32    // max atom types (spec: 10)
#define HST 68     // LDS row stride in shorts (conflict-free b16 stores, r11)
#define TPB 2      // sequential tiles per edge_fused workgroup

__device__ __forceinline__ float silu_f(float x) {
    float e = __expf(-x);
    return x * __builtin_amdgcn_rcpf(1.0f + e);
}
__device__ __forceinline__ float silu_exact(float x) { return x / (1.0f + __expf(-x)); }

__device__ __forceinline__ unsigned short bf16r(float f) {
    union { float f; unsigned u; } v; v.f = f;
    return (unsigned short)((v.u + 0x7fffu + ((v.u >> 16) & 1u)) >> 16);
}
__device__ __forceinline__ unsigned pkcvt(float lo, float hi) {
    union { __hip_bfloat162 h; unsigned u; } v;
    v.h = __float22bfloat162_rn(float2{lo, hi});
    return v.u;
}
__device__ __forceinline__ float bflo(unsigned u) {
    union { unsigned u; float f; } v; v.u = u << 16; return v.f;
}
__device__ __forceinline__ float bfhi(unsigned u) {
    union { unsigned u; float f; } v; v.u = u & 0xffff0000u; return v.f;
}

// ---------------- setup: prep + tiny-MLP + {cnt-zero | histo} ----------------
__global__ __launch_bounds__(256) void setup_kernel(
    const float* __restrict__ gw4, const float* __restrict__ gb4,
    const float* __restrict__ gw1, const float* __restrict__ gw2,
    const float* __restrict__ gw3,
    unsigned short* __restrict__ W4pk, unsigned short* __restrict__ gw1Tp,
    unsigned short* __restrict__ gw2T, unsigned short* __restrict__ gw3T,
    unsigned short* __restrict__ gb4T2,
    const float* __restrict__ atom_table, int n_types,
    const float* __restrict__ fw1, const float* __restrict__ fb1,
    const float* __restrict__ fw2, const float* __restrict__ fb2,
    const float* __restrict__ fw3, const float* __restrict__ fb3,
    float* __restrict__ Ai10,
    const int* __restrict__ edge_dst, int* __restrict__ cnt_i,
    int* __restrict__ rank0, int n_edges, int n_atoms, int do_zero)
{
    __shared__ float s_h1[MAXT * 64];   // 8 KB (block 300 only)
    __shared__ float s_h2[MAXT * 32];   // 4 KB
    int b = blockIdx.x;
    int tid = threadIdx.x;

    if (b < 300) {
        int idx = b * 256 + tid;
        if (idx < 65536) {
            // read gw4 linearly (coalesced), scatter-write W4pk[p][u][k]
            int k = idx >> 10, col = idx & 1023;
            int p, u;
            if (col < 512)      { p = col >> 3;          u = col & 7; }
            else if (col < 768) { p = (col - 512) >> 2;  u = 8 + ((col - 512) & 3); }
            else                { p = (col - 768) >> 2;  u = 12 + ((col - 768) & 3); }
            W4pk[p * 1024 + u * 64 + k] = bf16r(gw4[idx]);
        } else if (idx < 67584) {
            int t = idx - 65536; int n = t >> 5, k = t & 31;
            gw1Tp[t] = (k < 8) ? bf16r(gw1[k * 64 + n]) : (unsigned short)0;
        } else if (idx < 71680) {
            int t = idx - 67584; int n = t >> 6, k = t & 63;
            gw2T[t] = bf16r(gw2[k * 64 + n]);
        } else if (idx < 75776) {
            int t = idx - 71680; int n = t >> 6, k = t & 63;
            gw3T[t] = bf16r(gw3[k * 64 + n]);
        } else if (idx < 76800) {
            int t = idx - 75776; int u = t >> 6, p = t & 63;
            int colb = (u < 8) ? (p * 8 + u)
                     : (u < 12) ? (512 + p * 4 + (u - 8))
                                : (768 + p * 4 + (u - 12));
            gb4T2[t] = bf16r(gb4[colb]);
        }
        return;
    }
    if (b == 300) {
        int nt = min(n_types, MAXT);
        for (int it = tid; it < nt * 64; it += 256) {
            int ty = it >> 6, k = it & 63;
            float h = fb1[k];
#pragma unroll
            for (int j = 0; j < 16; ++j) h += atom_table[ty * 16 + j] * fw1[j * 64 + k];
            s_h1[it] = silu_exact(h);
        }
        __syncthreads();
        for (int it = tid; it < nt * 32; it += 256) {
            int ty = it >> 5, t = it & 31;
            float h = fb2[t];
            for (int k = 0; k < 64; ++k) h += s_h1[ty * 64 + k] * fw2[k * 32 + t];
            s_h2[it] = silu_exact(h);
        }
        __syncthreads();
        for (int it = tid; it < nt * 8; it += 256) {
            int ty = it >> 3, u = it & 7;
            float h = fb3[u];
            for (int k = 0; k < 32; ++k) h += s_h2[ty * 32 + k] * fw3[k * 8 + u];
            Ai10[it] = h;
        }
        return;
    }
    if (do_zero) {
        int i = (b - 301) * 256 + tid;
        if (i < n_atoms) cnt_i[i] = 0;
        return;
    }
    // CSR fallback path: rank0 histogram (cnt pre-zeroed by hipMemsetAsync)
    int e = (b - 301) * 256 + tid;
    if (e < n_edges) rank0[e] = atomicAdd(&cnt_i[edge_dst[e]], 1);
}

// ---------------- scan (CSR fallback path only): off = exclusive prefix ------
__global__ __launch_bounds__(1024) void scan_kernel(
    const int* __restrict__ cnt, int* __restrict__ off, int n)
{
    __shared__ int s[1024];
    int tid = threadIdx.x;
    int chunk = (n + 1023) / 1024;
    int start = tid * chunk;
    int end = min(start + chunk, n);
    int sum = 0;
    for (int i = start; i < end; ++i) sum += cnt[i];
    s[tid] = sum;
    __syncthreads();
    for (int d = 1; d < 1024; d <<= 1) {
        int v = (tid >= d) ? s[tid - d] : 0;
        __syncthreads();
        s[tid] += v;
        __syncthreads();
    }
    int run = (tid == 0) ? 0 : s[tid - 1];
    for (int i = start; i < end; ++i) {
        off[i] = run; run += cnt[i];
    }
    if (tid == 1023) off[n] = s[1023];
}

// ---------------- fused edge kernel: ONE WAVE, TPB sequential tiles ----------
// Per-tile body is the r15 kernel verbatim; LDS reused serially across tiles.
__global__ __launch_bounds__(64, 4) void edge_fused(
    const float* __restrict__ pos, const float* __restrict__ edge_shifts,
    const float* __restrict__ cell, const int* __restrict__ batch,
    const int* __restrict__ edge_src, const int* __restrict__ edge_dst,
    const int* __restrict__ A, const float* __restrict__ Ai10,
    const float* __restrict__ gb1, const float* __restrict__ gb2,
    const float* __restrict__ gb3,
    const unsigned short* __restrict__ gw1Tp, const unsigned short* __restrict__ gw2T,
    const unsigned short* __restrict__ gw3T,
    const unsigned short* __restrict__ W4pk, const unsigned short* __restrict__ gb4T2,
    const int* __restrict__ off, const int* __restrict__ rank0,
    int* __restrict__ cnt_i,
    float* __restrict__ erow, int n_edges, int col_n, int erow_st)
{
    // union: phase A h-buffer [64 rows][HST] shorts; phase B c-buffer [32][HST] u32
    __shared__ __align__(16) char smem[64 * HST * 2];
    unsigned short* s_hh = (unsigned short*)smem;
    unsigned* s_c2 = (unsigned*)smem;

    int lane = threadIdx.x;
    int quad = lane >> 4, col = lane & 15;

#pragma unroll 1
    for (int tt = 0; tt < TPB; ++tt) {
        int eb = (blockIdx.x * TPB + tt) * 64;
        if (eb >= n_edges) break;

        int ec = min(eb + lane, n_edges - 1);
        int src = edge_src[ec], dst = edge_dst[ec];
        // slot acquisition: issued here, first USED in the epilogue
        int rk;
        if (col_n) {
            int slot = (eb + lane < n_edges) ? atomicAdd(&cnt_i[dst], 1) : 0;
            rk = min(slot, MAXD - 1) * col_n + dst;
        } else {
            rk = off[dst] + rank0[ec];
        }
        int tsrc = A[src], tdst = A[dst];   // hoisted: latency hidden under phase A

        uint4 em4;
        float sh0, sh1, sh2, sh3, sh4, sh5, sh6, sh7, sh8;   // written at epilogue
        {   // phase 0: geometry -> emb (regs) + sh (regs)
            int b = batch[src];
            const float* C = cell + b * 9;
            float es0 = edge_shifts[ec * 3 + 0];
            float es1 = edge_shifts[ec * 3 + 1];
            float es2 = edge_shifts[ec * 3 + 2];
            float vx = pos[dst * 3 + 0] - pos[src * 3 + 0] + es0 * C[0] + es1 * C[3] + es2 * C[6];
            float vy = pos[dst * 3 + 1] - pos[src * 3 + 1] + es0 * C[1] + es1 * C[4] + es2 * C[7];
            float vz = pos[dst * 3 + 2] - pos[src * 3 + 2] + es0 * C[2] + es1 * C[5] + es2 * C[8];
            float r2 = vx * vx + vy * vy + vz * vz + 1e-12f;
            float r = sqrtf(r2);
            float inv = 1.0f / r;
            float x = vx * inv, y = vy * inv, z = vz * inv;

            float xr = fminf(r * 0.2f, 1.0f);
            float cutoff = (r <= 5.0f) ? 2.8284271247461903f : 0.0f;
            float em[8];
#pragma unroll
            for (int k = 0; k < 8; ++k) {
                float d = (xr - (float)k * (1.0f / 7.0f)) * 7.0f;
                em[k] = __expf(-0.5f * d * d) * cutoff;
            }
            em4 = make_uint4(pkcvt(em[0], em[1]), pkcvt(em[2], em[3]),
                             pkcvt(em[4], em[5]), pkcvt(em[6], em[7]));

            const float s3 = 1.7320508075688772f;
            const float s5 = 2.23606797749979f;
            const float s15 = 3.872983346207417f;
            sh0 = 1.0f;          sh1 = s3 * x;       sh2 = s3 * y;      sh3 = s3 * z;
            sh4 = s15 * x * y;   sh5 = s15 * y * z;
            sh6 = 0.5f * s5 * (2.0f * z * z - x * x - y * y);
            sh7 = s15 * x * z;   sh8 = 0.5f * s15 * (x * x - y * y);
        }

        // ---- phase A, layer 1: A-frag via shfl (quad 0 holds k<8, rest zero)
#pragma unroll
        for (int s = 0; s < 4; ++s) {
            int sl = s * 16 + col;   // lane owning this edge
            union { unsigned u[4]; short8 s8; } ua;
            ua.u[0] = (unsigned)__shfl((int)em4.x, sl, 64);
            ua.u[1] = (unsigned)__shfl((int)em4.y, sl, 64);
            ua.u[2] = (unsigned)__shfl((int)em4.z, sl, 64);
            ua.u[3] = (unsigned)__shfl((int)em4.w, sl, 64);
            short8 a = ua.s8;
            if (quad != 0) {
                short8 z = {0, 0, 0, 0, 0, 0, 0, 0};
                a = z;
            }
#pragma unroll
            for (int nt = 0; nt < 4; ++nt) {
                int n = nt * 16 + col;
                short8 b = *(const short8*)(gw1Tp + n * 32 + quad * 8);
                float bb = gb1[n];
                f32x4 d = {bb, bb, bb, bb};
                d = __builtin_amdgcn_mfma_f32_16x16x32_bf16(a, b, d, 0, 0, 0);
                unsigned u01 = pkcvt(silu_f(d[0]), silu_f(d[1]));
                unsigned u23 = pkcvt(silu_f(d[2]), silu_f(d[3]));
                unsigned short* bp2 = &s_hh[(s * 16 + quad * 4) * HST + n];
                bp2[0]       = (unsigned short)(u01 & 0xffffu);
                bp2[HST]     = (unsigned short)(u01 >> 16);
                bp2[2 * HST] = (unsigned short)(u23 & 0xffffu);
                bp2[3 * HST] = (unsigned short)(u23 >> 16);
            }
        }

        // ---- phase A, layers 2 and 3 (wave-private LDS round trips)
#pragma unroll 1
        for (int layer = 0; layer < 2; ++layer) {
            const unsigned short* WT = layer ? gw3T : gw2T;
            const float* gb = layer ? gb3 : gb2;

            short8 a0[4], a1[4];
#pragma unroll
            for (int s = 0; s < 4; ++s) {
                a0[s] = *(const short8*)&s_hh[(s * 16 + col) * HST + quad * 8];
                a1[s] = *(const short8*)&s_hh[(s * 16 + col) * HST + 32 + quad * 8];
            }

#pragma unroll
            for (int nt = 0; nt < 4; ++nt) {
                int n = nt * 16 + col;
                short8 b0 = *(const short8*)(WT + n * 64 + quad * 8);
                short8 b1 = *(const short8*)(WT + n * 64 + 32 + quad * 8);
                float bb = gb[n];
#pragma unroll
                for (int s = 0; s < 4; ++s) {
                    f32x4 d = {bb, bb, bb, bb};
                    d = __builtin_amdgcn_mfma_f32_16x16x32_bf16(a0[s], b0, d, 0, 0, 0);
                    d = __builtin_amdgcn_mfma_f32_16x16x32_bf16(a1[s], b1, d, 0, 0, 0);
                    unsigned u01 = pkcvt(silu_f(d[0]), silu_f(d[1]));
                    unsigned u23 = pkcvt(silu_f(d[2]), silu_f(d[3]));
                    unsigned short* bp2 = &s_hh[(s * 16 + quad * 4) * HST + n];
                    bp2[0]       = (unsigned short)(u01 & 0xffffu);
                    bp2[HST]     = (unsigned short)(u01 >> 16);
                    bp2[2 * HST] = (unsigned short)(u23 & 0xffffu);
                    bp2[3 * HST] = (unsigned short)(u23 >> 16);
                }
            }
        }

        // ---- h3 A-frags to registers (in-order DS pipe)
        short8 aH0[4], aH1[4];
#pragma unroll
        for (int s = 0; s < 4; ++s) {
            aH0[s] = *(const short8*)&s_hh[(s * 16 + col) * HST + quad * 8];
            aH1[s] = *(const short8*)&s_hh[(s * 16 + col) * HST + 32 + quad * 8];
        }

        // ---- phase B prep: pair-packed c[pp][e] bf16x2 (overwrites h-buffer)
        {
            const float4* asp = (const float4*)(Ai10 + (size_t)tsrc * 8);
            float4 A0 = asp[0], A1 = asp[1];
            const float4* adp = (const float4*)(Ai10 + (size_t)tdst * 8);
            float4 B0 = adp[0], B1 = adp[1];
            float as[8] = {A0.x, A0.y, A0.z, A0.w, A1.x, A1.y, A1.z, A1.w};
            float ad[8] = {B0.x, B0.y, B0.z, B0.w, B1.x, B1.y, B1.z, B1.w};
#pragma unroll
            for (int pp = 0; pp < 32; ++pp) {
                int p = pp * 2;
                float av = as[p >> 3];
                s_c2[pp * HST + lane] = pkcvt(av * ad[p & 7], av * ad[(p & 7) + 1]);
            }
        }

        // ---- bias GEMM: g = c @ gb4T2^T  (A from s_c2, K=64)
        f32x4 g[4];
        {
            const unsigned short* bbp = gb4T2 + col * 64 + quad * 8;
            short8 b0 = *(const short8*)bbp;
            short8 b1 = *(const short8*)(bbp + 32);
            f32x4 zero4 = {0.0f, 0.0f, 0.0f, 0.0f};
#pragma unroll
            for (int s = 0; s < 4; ++s) {
                int ebase = s * 16 + col;
                union { unsigned u[4]; short8 s8; } ua, ub;
#pragma unroll
                for (int t = 0; t < 4; ++t) ua.u[t] = s_c2[(quad * 4 + t) * HST + ebase];
#pragma unroll
                for (int t = 0; t < 4; ++t) ub.u[t] = s_c2[(16 + quad * 4 + t) * HST + ebase];
                f32x4 d = __builtin_amdgcn_mfma_f32_16x16x32_bf16(ua.s8, b0, zero4, 0, 0, 0);
                g[s] = __builtin_amdgcn_mfma_f32_16x16x32_bf16(ub.s8, b1, d, 0, 0, 0);
            }
        }

        // ---- main p-loop: 2-pair-deep B prefetch (8 KB in flight)
        const unsigned short* wb = W4pk + col * 64 + quad * 8;
        const char* cbase = (const char*)s_c2 + quad * 16;
        f32x4 zero4 = {0.0f, 0.0f, 0.0f, 0.0f};

        short8 Pb0[2], Pb1[2], Qb0[2], Qb1[2];
        Pb0[0] = *(const short8*)(wb);
        Pb1[0] = *(const short8*)(wb + 32);
        Qb0[0] = *(const short8*)(wb + 1024);
        Qb1[0] = *(const short8*)(wb + 1056);
        Pb0[1] = *(const short8*)(wb + 2048);
        Pb1[1] = *(const short8*)(wb + 2080);
        Qb0[1] = *(const short8*)(wb + 3072);
        Qb1[1] = *(const short8*)(wb + 3104);

#pragma unroll 2
        for (int pp = 0; pp < 32; ++pp) {
            int slot = pp & 1;
            short8 b0 = Pb0[slot], b1 = Pb1[slot], e0 = Qb0[slot], e1 = Qb1[slot];
            // prefetch pair pp+2 (tail overruns into gw1Tp/gw2T — harmless)
            const unsigned short* nw = wb + (2 * pp + 4) * 1024;
            Pb0[slot] = *(const short8*)(nw);
            Pb1[slot] = *(const short8*)(nw + 32);
            Qb0[slot] = *(const short8*)(nw + 1024);
            Qb1[slot] = *(const short8*)(nw + 1056);

            uint4 cc[4];
#pragma unroll
            for (int s = 0; s < 4; ++s)
                cc[s] = *(const uint4*)(cbase + pp * (HST * 4) + s * 64);

            f32x4 d[4], d2[4];
#pragma unroll
            for (int s = 0; s < 4; ++s) {
                f32x4 t = __builtin_amdgcn_mfma_f32_16x16x32_bf16(aH0[s], b0, zero4, 0, 0, 0);
                d[s] = __builtin_amdgcn_mfma_f32_16x16x32_bf16(aH1[s], b1, t, 0, 0, 0);
            }
#pragma unroll
            for (int s = 0; s < 4; ++s) {
                f32x4 t = __builtin_amdgcn_mfma_f32_16x16x32_bf16(aH0[s], e0, zero4, 0, 0, 0);
                d2[s] = __builtin_amdgcn_mfma_f32_16x16x32_bf16(aH1[s], e1, t, 0, 0, 0);
            }
#pragma unroll
            for (int s = 0; s < 4; ++s) {
                const unsigned* cu = (const unsigned*)&cc[s];
#pragma unroll
                for (int r = 0; r < 4; ++r) {
                    unsigned u = cu[r];
                    g[s][r] += bflo(u) * d[s][r];
                    g[s][r] += bfhi(u) * d2[s][r];
                }
            }
        }

        // ---- epilogue: sh write (own row) + slot-ordered g writes
        if (eb + lane < n_edges) {
            float* op = erow + (size_t)rk * erow_st + 16;
            *(float4*)op       = float4{sh0, sh1, sh2, sh3};
            *(float4*)(op + 4) = float4{sh4, sh5, sh6, sh7};
            op[8] = sh8;
        }
        const float alpha = 0.125f;
#pragma unroll
        for (int s = 0; s < 4; ++s) {
#pragma unroll
            for (int r = 0; r < 4; ++r) {
                int el = s * 16 + quad * 4 + r;
                int rkv = __shfl(rk, el, 64);
                if (eb + el < n_edges)
                    erow[(size_t)rkv * erow_st + col] = alpha * g[s][r];
            }
        }
        // LDS reuse across tiles: in-order wave-private DS pipe, no barrier
    }
}

// ---------------- gather: wave per atom, LDS-staged coalesced rows ----------
__global__ __launch_bounds__(256) void gather_kernel(
    const int* __restrict__ off, const int* __restrict__ cnt,
    const float* __restrict__ erow,
    float* __restrict__ out, int n_atoms, int col_n, int erow_st)
{
    __shared__ float s_rows[4][8][30];
    int w = threadIdx.x >> 6, lane = threadIdx.x & 63;
    int a = blockIdx.x * 4 + w;
    if (a >= n_atoms) return;
    int beg, count, count_rd;
    if (col_n) { beg = 0;      count = cnt[a];            count_rd = min(count, MAXD); }
    else       { beg = off[a]; count = off[a + 1] - beg;  count_rd = count; }

    int f = min(lane, 39);
    int u, shi;
    if (f < 8)       { u = f;                 shi = 0; }
    else if (f < 20) { u = 8 + (f - 8) / 3;   shi = 1 + (f - 8) % 3; }
    else             { u = 12 + (f - 20) / 5; shi = 4 + (f - 20) % 5; }

    int rsub = lane >> 3, csub = lane & 7;   // lane stages row rsub, dwords csub*4..+4
    float val = 0.0f;
    for (int i = 0; i < count_rd; i += 8) {
        int nr = min(8, count_rd - i);
        int j = i + rsub;
        bool ok = (j < count_rd);
        size_t ri = col_n ? ((size_t)j * col_n + a) : (size_t)(beg + j);
        if (csub < 7) {   // 28 dwords per row
            float4 v = ok ? *(const float4*)(erow + ri * erow_st + csub * 4)
                          : float4{0.0f, 0.0f, 0.0f, 0.0f};
            *(float2*)&s_rows[w][rsub][csub * 4]     = float2{v.x, v.y};
            *(float2*)&s_rows[w][rsub][csub * 4 + 2] = float2{v.z, v.w};
        }
        // wave-private LDS slice: compiler waitcnt suffices, no barrier
#pragma unroll
        for (int jj = 0; jj < 8; ++jj) {
            float prod = s_rows[w][jj][u] * s_rows[w][jj][16 + shi];
            val += (jj < nr) ? prod : 0.0f;
        }
    }
    if (lane < 40) {
        float c = (float)max(count, 1);
        out[(size_t)a * 40 + lane] = val / c;
    }
}

static inline size_t align256(size_t x) { return (x + 255) & ~(size_t)255; }

extern "C" void kernel_launch(void* const* d_in, const int* in_sizes, int n_in,
                              void* d_out, int out_size, void* d_ws, size_t ws_size,
                              hipStream_t stream)
{
    const float* pos         = (const float*)d_in[0];
    const float* edge_shifts = (const float*)d_in[1];
    const float* cell        = (const float*)d_in[2];
    const float* atom_table  = (const float*)d_in[3];
    const float* fw1 = (const float*)d_in[4];
    const float* fb1 = (const float*)d_in[5];
    const float* fw2 = (const float*)d_in[6];
    const float* fb2 = (const float*)d_in[7];
    const float* fw3 = (const float*)d_in[8];
    const float* fb3 = (const float*)d_in[9];
    const float* gw1 = (const float*)d_in[10];
    const float* gb1 = (const float*)d_in[11];
    const float* gw2 = (const float*)d_in[12];
    const float* gb2 = (const float*)d_in[13];
    const float* gw3 = (const float*)d_in[14];
    const float* gb3 = (const float*)d_in[15];
    const float* gw4 = (const float*)d_in[16];
    const float* gb4 = (const float*)d_in[17];
    const int* A        = (const int*)d_in[18];
    const int* batch    = (const int*)d_in[19];
    const int* edge_src = (const int*)d_in[20];
    const int* edge_dst = (const int*)d_in[21];

    int n_atoms = in_sizes[18];
    int n_edges = in_sizes[20];
    int n_types = in_sizes[3] / 16;   // atom_table rows (EMB=16); spec: 10

    char* w = (char*)d_ws;
    float* Ai10 = (float*)w;                    w += align256((size_t)MAXT * 8 * 4);
    int* cnt_i = (int*)w;                       w += align256((size_t)n_atoms * 4);
    int* off = (int*)w;                         w += align256((size_t)(n_atoms + 1) * 4);
    int* rank0 = (int*)w;                       w += align256((size_t)n_edges * 4);
    unsigned short* W4pk = (unsigned short*)w;  w += align256((size_t)65536 * 2);
    unsigned short* gw1Tp = (unsigned short*)w; w += align256((size_t)2048 * 2);
    unsigned short* gw2T = (unsigned short*)w;  w += align256((size_t)4096 * 2);
    unsigned short* gw3T = (unsigned short*)w;  w += align256((size_t)4096 * 2);
    unsigned short* gb4T2 = (unsigned short*)w; w += align256((size_t)1024 * 2);
    float* erow = (float*)w;                    // last: variable size

    float* out = (float*)d_out;

    // Path selection by workspace size (r13/r14-proven): col-major needs
    // n_atoms*MAXD*EROWC floats; fallback = CSR path (memset+histo+scan).
    size_t used = (size_t)((char*)erow - (char*)d_ws);
    size_t need_col = (size_t)n_atoms * MAXD * EROWC * 4;
    int col_n = 0, erow_st = EROW;
    if (ws_size >= used + need_col) { col_n = n_atoms; erow_st = EROWC; }

    int e_blk = (n_edges + 255) / 256;
    int z_blk = (n_atoms + 255) / 256;

    if (col_n) {
        // 3 nodes: setup(prep+MLP+zero) -> edge(cursor, 2 tiles/WG) -> gather
        setup_kernel<<<301 + z_blk, 256, 0, stream>>>(
            gw4, gb4, gw1, gw2, gw3, W4pk, gw1Tp, gw2T, gw3T, gb4T2,
            atom_table, n_types, fw1, fb1, fw2, fb2, fw3, fb3, Ai10,
            edge_dst, cnt_i, rank0, n_edges, n_atoms, /*do_zero=*/1);
    } else {
        hipMemsetAsync(cnt_i, 0, sizeof(int) * (size_t)n_atoms, stream);
        setup_kernel<<<301 + e_blk, 256, 0, stream>>>(
            gw4, gb4, gw1, gw2, gw3, W4pk, gw1Tp, gw2T, gw3T, gb4T2,
            atom_table, n_types, fw1, fb1, fw2, fb2, fw3, fb3, Ai10,
            edge_dst, cnt_i, rank0, n_edges, n_atoms, /*do_zero=*/0);
        scan_kernel<<<1, 1024, 0, stream>>>(cnt_i, off, n_atoms);
    }

    int n_tiles = (n_edges + 63) / 64;
    edge_fused<<<(n_tiles + TPB - 1) / TPB, 64, 0, stream>>>(
        pos, edge_shifts, cell, batch, edge_src, edge_dst, A, Ai10,
        gb1, gb2, gb3, gw1Tp, gw2T, gw3T, W4pk, gb4T2, off, rank0,
        cnt_i, erow, n_edges, col_n, erow_st);

    gather_kernel<<<(n_atoms + 3) / 4, 256, 0, stream>>>(
        off, cnt_i, erow, out, n_atoms, col_n, erow_st);
}

// Round 17
// 252.892 us; speedup vs baseline: 1.1078x; 1.1078x over previous
//
#include <hip/hip_runtime.h>
#include <hip/hip_bf16.h>
#include <math.h>

// N=25000, E=400000, S=8, NB=8, RMAX=5, EMB=16, MULS=(8,4,4), DIMS=(1,3,5), WNUM=1024
// g[e,u] = sum_p c[e,p] * ( sum_k h3[e,k] gw4[k, col(p,u)] + gb4[col(p,u)] )
// out[a, f(u,m)] = (1/cnt[a]) * sum_{e: dst=a} alpha * g[e,u] * sh[e, m]
//
// r17 = r15 verbatim (session best, 255.4 µs): 3-node col-major pipeline
// setup(prep + tiny-MLP + cnt-zeroing) -> edge_fused(cnt-as-cursor slots)
// -> gather. r16's sequential 2-tile variant REVERTED (it broke cross-wave
// L2 residency of W4pk: FETCH 6.8->49.7 MB, edge 160->184 µs).
// CSR fallback (ws too small) keeps memset + histo + scan.

typedef __attribute__((ext_vector_type(8))) short short8;
typedef __attribute__((ext_vector_type(4))) float f32x4;

#define EROW 28    // CSR row stride (floats): g[16]+sh[9]+pad
#define EROWC 32   // col-major row stride (floats): 128 B = 2 cache lines
#define MAXD 48    // col-major slots/atom; P(Poisson(16) >= 48) ~ 5e-12/atom
#define MAXT 32    // max atom types (spec: 10)
#define HST 68     // LDS row stride in shorts (conflict-free b16 stores, r11)

__device__ __forceinline__ float silu_f(float x) {
    float e = __expf(-x);
    return x * __builtin_amdgcn_rcpf(1.0f + e);
}
__device__ __forceinline__ float silu_exact(float x) { return x / (1.0f + __expf(-x)); }

__device__ __forceinline__ unsigned short bf16r(float f) {
    union { float f; unsigned u; } v; v.f = f;
    return (unsigned short)((v.u + 0x7fffu + ((v.u >> 16) & 1u)) >> 16);
}
__device__ __forceinline__ unsigned pkcvt(float lo, float hi) {
    union { __hip_bfloat162 h; unsigned u; } v;
    v.h = __float22bfloat162_rn(float2{lo, hi});
    return v.u;
}
__device__ __forceinline__ float bflo(unsigned u) {
    union { unsigned u; float f; } v; v.u = u << 16; return v.f;
}
__device__ __forceinline__ float bfhi(unsigned u) {
    union { unsigned u; float f; } v; v.u = u & 0xffff0000u; return v.f;
}

// ---------------- setup: prep + tiny-MLP + {cnt-zero | histo} ----------------
// blocks [0,300): prep; block 300: tiny MLP (LDS-staged, spill-proof);
// blocks >300: col path -> zero cnt; CSR fallback -> rank0 histogram.
__global__ __launch_bounds__(256) void setup_kernel(
    const float* __restrict__ gw4, const float* __restrict__ gb4,
    const float* __restrict__ gw1, const float* __restrict__ gw2,
    const float* __restrict__ gw3,
    unsigned short* __restrict__ W4pk, unsigned short* __restrict__ gw1Tp,
    unsigned short* __restrict__ gw2T, unsigned short* __restrict__ gw3T,
    unsigned short* __restrict__ gb4T2,
    const float* __restrict__ atom_table, int n_types,
    const float* __restrict__ fw1, const float* __restrict__ fb1,
    const float* __restrict__ fw2, const float* __restrict__ fb2,
    const float* __restrict__ fw3, const float* __restrict__ fb3,
    float* __restrict__ Ai10,
    const int* __restrict__ edge_dst, int* __restrict__ cnt_i,
    int* __restrict__ rank0, int n_edges, int n_atoms, int do_zero)
{
    __shared__ float s_h1[MAXT * 64];   // 8 KB (block 300 only)
    __shared__ float s_h2[MAXT * 32];   // 4 KB
    int b = blockIdx.x;
    int tid = threadIdx.x;

    if (b < 300) {
        int idx = b * 256 + tid;
        if (idx < 65536) {
            // read gw4 linearly (coalesced), scatter-write W4pk[p][u][k]
            int k = idx >> 10, col = idx & 1023;
            int p, u;
            if (col < 512)      { p = col >> 3;          u = col & 7; }
            else if (col < 768) { p = (col - 512) >> 2;  u = 8 + ((col - 512) & 3); }
            else                { p = (col - 768) >> 2;  u = 12 + ((col - 768) & 3); }
            W4pk[p * 1024 + u * 64 + k] = bf16r(gw4[idx]);
        } else if (idx < 67584) {
            int t = idx - 65536; int n = t >> 5, k = t & 31;
            gw1Tp[t] = (k < 8) ? bf16r(gw1[k * 64 + n]) : (unsigned short)0;
        } else if (idx < 71680) {
            int t = idx - 67584; int n = t >> 6, k = t & 63;
            gw2T[t] = bf16r(gw2[k * 64 + n]);
        } else if (idx < 75776) {
            int t = idx - 71680; int n = t >> 6, k = t & 63;
            gw3T[t] = bf16r(gw3[k * 64 + n]);
        } else if (idx < 76800) {
            int t = idx - 75776; int u = t >> 6, p = t & 63;
            int colb = (u < 8) ? (p * 8 + u)
                     : (u < 12) ? (512 + p * 4 + (u - 8))
                                : (768 + p * 4 + (u - 12));
            gb4T2[t] = bf16r(gb4[colb]);
        }
        return;
    }
    if (b == 300) {
        int nt = min(n_types, MAXT);
        for (int it = tid; it < nt * 64; it += 256) {
            int ty = it >> 6, k = it & 63;
            float h = fb1[k];
#pragma unroll
            for (int j = 0; j < 16; ++j) h += atom_table[ty * 16 + j] * fw1[j * 64 + k];
            s_h1[it] = silu_exact(h);
        }
        __syncthreads();
        for (int it = tid; it < nt * 32; it += 256) {
            int ty = it >> 5, t = it & 31;
            float h = fb2[t];
            for (int k = 0; k < 64; ++k) h += s_h1[ty * 64 + k] * fw2[k * 32 + t];
            s_h2[it] = silu_exact(h);
        }
        __syncthreads();
        for (int it = tid; it < nt * 8; it += 256) {
            int ty = it >> 3, u = it & 7;
            float h = fb3[u];
            for (int k = 0; k < 32; ++k) h += s_h2[ty * 32 + k] * fw3[k * 8 + u];
            Ai10[it] = h;
        }
        return;
    }
    if (do_zero) {
        // col-major path: zero cnt here (edge's cursor atomics run in the NEXT
        // kernel, so no intra-kernel ordering needed)
        int i = (b - 301) * 256 + tid;
        if (i < n_atoms) cnt_i[i] = 0;
        return;
    }
    // CSR fallback path: rank0 histogram (cnt pre-zeroed by hipMemsetAsync)
    int e = (b - 301) * 256 + tid;
    if (e < n_edges) rank0[e] = atomicAdd(&cnt_i[edge_dst[e]], 1);
}

// ---------------- scan (CSR fallback path only): off = exclusive prefix ------
__global__ __launch_bounds__(1024) void scan_kernel(
    const int* __restrict__ cnt, int* __restrict__ off, int n)
{
    __shared__ int s[1024];
    int tid = threadIdx.x;
    int chunk = (n + 1023) / 1024;
    int start = tid * chunk;
    int end = min(start + chunk, n);
    int sum = 0;
    for (int i = start; i < end; ++i) sum += cnt[i];
    s[tid] = sum;
    __syncthreads();
    for (int d = 1; d < 1024; d <<= 1) {
        int v = (tid >= d) ? s[tid - d] : 0;
        __syncthreads();
        s[tid] += v;
        __syncthreads();
    }
    int run = (tid == 0) ? 0 : s[tid - 1];
    for (int i = start; i < end; ++i) {
        off[i] = run; run += cnt[i];
    }
    if (tid == 1023) off[n] = s[1023];
}

// ---------------- fused edge kernel: ONE WAVE per workgroup ----------------
// col_n != 0 -> slot = atomicAdd(&cnt[dst],1) issued EARLY, first used in the
// epilogue (sh carried in 9 regs; r10/r14-proven). Fallback: off[dst]+rank0.
__global__ __launch_bounds__(64, 4) void edge_fused(
    const float* __restrict__ pos, const float* __restrict__ edge_shifts,
    const float* __restrict__ cell, const int* __restrict__ batch,
    const int* __restrict__ edge_src, const int* __restrict__ edge_dst,
    const int* __restrict__ A, const float* __restrict__ Ai10,
    const float* __restrict__ gb1, const float* __restrict__ gb2,
    const float* __restrict__ gb3,
    const unsigned short* __restrict__ gw1Tp, const unsigned short* __restrict__ gw2T,
    const unsigned short* __restrict__ gw3T,
    const unsigned short* __restrict__ W4pk, const unsigned short* __restrict__ gb4T2,
    const int* __restrict__ off, const int* __restrict__ rank0,
    int* __restrict__ cnt_i,
    float* __restrict__ erow, int n_edges, int col_n, int erow_st)
{
    // union: phase A h-buffer [64 rows][HST] shorts; phase B c-buffer [32][HST] u32
    __shared__ __align__(16) char smem[64 * HST * 2];
    unsigned short* s_hh = (unsigned short*)smem;
    unsigned* s_c2 = (unsigned*)smem;

    int lane = threadIdx.x;
    int eb = blockIdx.x * 64;
    int quad = lane >> 4, col = lane & 15;

    int ec = min(eb + lane, n_edges - 1);
    int src = edge_src[ec], dst = edge_dst[ec];
    // slot acquisition: issued here, first USED in the epilogue (latency hidden)
    int rk;
    if (col_n) {
        int slot = (eb + lane < n_edges) ? atomicAdd(&cnt_i[dst], 1) : 0;
        rk = min(slot, MAXD - 1) * col_n + dst;
    } else {
        rk = off[dst] + rank0[ec];
    }
    int tsrc = A[src], tdst = A[dst];   // hoisted: latency hidden under phase A

    uint4 em4;
    float sh0, sh1, sh2, sh3, sh4, sh5, sh6, sh7, sh8;   // written at epilogue
    {   // phase 0: geometry -> emb (regs) + sh (regs)
        int b = batch[src];
        const float* C = cell + b * 9;
        float es0 = edge_shifts[ec * 3 + 0];
        float es1 = edge_shifts[ec * 3 + 1];
        float es2 = edge_shifts[ec * 3 + 2];
        float vx = pos[dst * 3 + 0] - pos[src * 3 + 0] + es0 * C[0] + es1 * C[3] + es2 * C[6];
        float vy = pos[dst * 3 + 1] - pos[src * 3 + 1] + es0 * C[1] + es1 * C[4] + es2 * C[7];
        float vz = pos[dst * 3 + 2] - pos[src * 3 + 2] + es0 * C[2] + es1 * C[5] + es2 * C[8];
        float r2 = vx * vx + vy * vy + vz * vz + 1e-12f;
        float r = sqrtf(r2);
        float inv = 1.0f / r;
        float x = vx * inv, y = vy * inv, z = vz * inv;

        float xr = fminf(r * 0.2f, 1.0f);
        float cutoff = (r <= 5.0f) ? 2.8284271247461903f : 0.0f;
        float em[8];
#pragma unroll
        for (int k = 0; k < 8; ++k) {
            float d = (xr - (float)k * (1.0f / 7.0f)) * 7.0f;
            em[k] = __expf(-0.5f * d * d) * cutoff;
        }
        em4 = make_uint4(pkcvt(em[0], em[1]), pkcvt(em[2], em[3]),
                         pkcvt(em[4], em[5]), pkcvt(em[6], em[7]));

        const float s3 = 1.7320508075688772f;
        const float s5 = 2.23606797749979f;
        const float s15 = 3.872983346207417f;
        sh0 = 1.0f;          sh1 = s3 * x;       sh2 = s3 * y;      sh3 = s3 * z;
        sh4 = s15 * x * y;   sh5 = s15 * y * z;
        sh6 = 0.5f * s5 * (2.0f * z * z - x * x - y * y);
        sh7 = s15 * x * z;   sh8 = 0.5f * s15 * (x * x - y * y);
    }

    // ---- phase A, layer 1: A-frag via shfl (quad 0 holds k<8, rest zero)
#pragma unroll
    for (int s = 0; s < 4; ++s) {
        int sl = s * 16 + col;   // lane owning this edge
        union { unsigned u[4]; short8 s8; } ua;
        ua.u[0] = (unsigned)__shfl((int)em4.x, sl, 64);
        ua.u[1] = (unsigned)__shfl((int)em4.y, sl, 64);
        ua.u[2] = (unsigned)__shfl((int)em4.z, sl, 64);
        ua.u[3] = (unsigned)__shfl((int)em4.w, sl, 64);
        short8 a = ua.s8;
        if (quad != 0) {
            short8 z = {0, 0, 0, 0, 0, 0, 0, 0};
            a = z;
        }
#pragma unroll
        for (int nt = 0; nt < 4; ++nt) {
            int n = nt * 16 + col;
            short8 b = *(const short8*)(gw1Tp + n * 32 + quad * 8);
            float bb = gb1[n];
            f32x4 d = {bb, bb, bb, bb};
            d = __builtin_amdgcn_mfma_f32_16x16x32_bf16(a, b, d, 0, 0, 0);
            unsigned u01 = pkcvt(silu_f(d[0]), silu_f(d[1]));
            unsigned u23 = pkcvt(silu_f(d[2]), silu_f(d[3]));
            unsigned short* bp2 = &s_hh[(s * 16 + quad * 4) * HST + n];
            bp2[0]       = (unsigned short)(u01 & 0xffffu);
            bp2[HST]     = (unsigned short)(u01 >> 16);
            bp2[2 * HST] = (unsigned short)(u23 & 0xffffu);
            bp2[3 * HST] = (unsigned short)(u23 >> 16);
        }
    }

    // ---- phase A, layers 2 and 3 (wave-private LDS round trips)
#pragma unroll 1
    for (int layer = 0; layer < 2; ++layer) {
        const unsigned short* WT = layer ? gw3T : gw2T;
        const float* gb = layer ? gb3 : gb2;

        short8 a0[4], a1[4];
#pragma unroll
        for (int s = 0; s < 4; ++s) {
            a0[s] = *(const short8*)&s_hh[(s * 16 + col) * HST + quad * 8];
            a1[s] = *(const short8*)&s_hh[(s * 16 + col) * HST + 32 + quad * 8];
        }

#pragma unroll
        for (int nt = 0; nt < 4; ++nt) {
            int n = nt * 16 + col;
            short8 b0 = *(const short8*)(WT + n * 64 + quad * 8);
            short8 b1 = *(const short8*)(WT + n * 64 + 32 + quad * 8);
            float bb = gb[n];
#pragma unroll
            for (int s = 0; s < 4; ++s) {
                f32x4 d = {bb, bb, bb, bb};
                d = __builtin_amdgcn_mfma_f32_16x16x32_bf16(a0[s], b0, d, 0, 0, 0);
                d = __builtin_amdgcn_mfma_f32_16x16x32_bf16(a1[s], b1, d, 0, 0, 0);
                unsigned u01 = pkcvt(silu_f(d[0]), silu_f(d[1]));
                unsigned u23 = pkcvt(silu_f(d[2]), silu_f(d[3]));
                unsigned short* bp2 = &s_hh[(s * 16 + quad * 4) * HST + n];
                bp2[0]       = (unsigned short)(u01 & 0xffffu);
                bp2[HST]     = (unsigned short)(u01 >> 16);
                bp2[2 * HST] = (unsigned short)(u23 & 0xffffu);
                bp2[3 * HST] = (unsigned short)(u23 >> 16);
            }
        }
    }

    // ---- h3 A-frags to registers (in-order DS pipe: reads precede c overwrites)
    short8 aH0[4], aH1[4];
#pragma unroll
    for (int s = 0; s < 4; ++s) {
        aH0[s] = *(const short8*)&s_hh[(s * 16 + col) * HST + quad * 8];
        aH1[s] = *(const short8*)&s_hh[(s * 16 + col) * HST + 32 + quad * 8];
    }

    // ---- phase B prep: pair-packed c[pp][e] bf16x2 (overwrites h-buffer)
    {
        const float4* asp = (const float4*)(Ai10 + (size_t)tsrc * 8);
        float4 A0 = asp[0], A1 = asp[1];
        const float4* adp = (const float4*)(Ai10 + (size_t)tdst * 8);
        float4 B0 = adp[0], B1 = adp[1];
        float as[8] = {A0.x, A0.y, A0.z, A0.w, A1.x, A1.y, A1.z, A1.w};
        float ad[8] = {B0.x, B0.y, B0.z, B0.w, B1.x, B1.y, B1.z, B1.w};
#pragma unroll
        for (int pp = 0; pp < 32; ++pp) {
            int p = pp * 2;
            float av = as[p >> 3];
            s_c2[pp * HST + lane] = pkcvt(av * ad[p & 7], av * ad[(p & 7) + 1]);
        }
    }

    // ---- bias GEMM: g = c @ gb4T2^T  (A from s_c2, K=64)
    f32x4 g[4];
    {
        const unsigned short* bbp = gb4T2 + col * 64 + quad * 8;
        short8 b0 = *(const short8*)bbp;
        short8 b1 = *(const short8*)(bbp + 32);
        f32x4 zero4 = {0.0f, 0.0f, 0.0f, 0.0f};
#pragma unroll
        for (int s = 0; s < 4; ++s) {
            int ebase = s * 16 + col;
            union { unsigned u[4]; short8 s8; } ua, ub;
#pragma unroll
            for (int t = 0; t < 4; ++t) ua.u[t] = s_c2[(quad * 4 + t) * HST + ebase];
#pragma unroll
            for (int t = 0; t < 4; ++t) ub.u[t] = s_c2[(16 + quad * 4 + t) * HST + ebase];
            f32x4 d = __builtin_amdgcn_mfma_f32_16x16x32_bf16(ua.s8, b0, zero4, 0, 0, 0);
            g[s] = __builtin_amdgcn_mfma_f32_16x16x32_bf16(ub.s8, b1, d, 0, 0, 0);
        }
    }

    // ---- main p-loop: 2-pair-deep B prefetch (8 KB in flight)
    const unsigned short* wb = W4pk + col * 64 + quad * 8;
    const char* cbase = (const char*)s_c2 + quad * 16;
    f32x4 zero4 = {0.0f, 0.0f, 0.0f, 0.0f};

    short8 Pb0[2], Pb1[2], Qb0[2], Qb1[2];
    Pb0[0] = *(const short8*)(wb);
    Pb1[0] = *(const short8*)(wb + 32);
    Qb0[0] = *(const short8*)(wb + 1024);
    Qb1[0] = *(const short8*)(wb + 1056);
    Pb0[1] = *(const short8*)(wb + 2048);
    Pb1[1] = *(const short8*)(wb + 2080);
    Qb0[1] = *(const short8*)(wb + 3072);
    Qb1[1] = *(const short8*)(wb + 3104);

#pragma unroll 2
    for (int pp = 0; pp < 32; ++pp) {
        int slot = pp & 1;
        short8 b0 = Pb0[slot], b1 = Pb1[slot], e0 = Qb0[slot], e1 = Qb1[slot];
        // prefetch pair pp+2 (tail overruns into gw1Tp/gw2T — harmless)
        const unsigned short* nw = wb + (2 * pp + 4) * 1024;
        Pb0[slot] = *(const short8*)(nw);
        Pb1[slot] = *(const short8*)(nw + 32);
        Qb0[slot] = *(const short8*)(nw + 1024);
        Qb1[slot] = *(const short8*)(nw + 1056);

        uint4 cc[4];
#pragma unroll
        for (int s = 0; s < 4; ++s)
            cc[s] = *(const uint4*)(cbase + pp * (HST * 4) + s * 64);

        f32x4 d[4], d2[4];
#pragma unroll
        for (int s = 0; s < 4; ++s) {
            f32x4 t = __builtin_amdgcn_mfma_f32_16x16x32_bf16(aH0[s], b0, zero4, 0, 0, 0);
            d[s] = __builtin_amdgcn_mfma_f32_16x16x32_bf16(aH1[s], b1, t, 0, 0, 0);
        }
#pragma unroll
        for (int s = 0; s < 4; ++s) {
            f32x4 t = __builtin_amdgcn_mfma_f32_16x16x32_bf16(aH0[s], e0, zero4, 0, 0, 0);
            d2[s] = __builtin_amdgcn_mfma_f32_16x16x32_bf16(aH1[s], e1, t, 0, 0, 0);
        }
#pragma unroll
        for (int s = 0; s < 4; ++s) {
            const unsigned* cu = (const unsigned*)&cc[s];
#pragma unroll
            for (int r = 0; r < 4; ++r) {
                unsigned u = cu[r];
                g[s][r] += bflo(u) * d[s][r];
                g[s][r] += bfhi(u) * d2[s][r];
            }
        }
    }

    // ---- epilogue: sh write (own row) + slot-ordered g writes (rank via shfl)
    if (eb + lane < n_edges) {
        float* op = erow + (size_t)rk * erow_st + 16;
        *(float4*)op       = float4{sh0, sh1, sh2, sh3};
        *(float4*)(op + 4) = float4{sh4, sh5, sh6, sh7};
        op[8] = sh8;
    }
    const float alpha = 0.125f;
#pragma unroll
    for (int s = 0; s < 4; ++s) {
#pragma unroll
        for (int r = 0; r < 4; ++r) {
            int el = s * 16 + quad * 4 + r;
            int rkv = __shfl(rk, el, 64);
            if (eb + el < n_edges)
                erow[(size_t)rkv * erow_st + col] = alpha * g[s][r];
        }
    }
}

// ---------------- gather: wave per atom, LDS-staged coalesced rows ----------
// col_n != 0 -> rows {j*col_n + a : j < min(cnt[a],MAXD)}; divide by true cnt.
__global__ __launch_bounds__(256) void gather_kernel(
    const int* __restrict__ off, const int* __restrict__ cnt,
    const float* __restrict__ erow,
    float* __restrict__ out, int n_atoms, int col_n, int erow_st)
{
    __shared__ float s_rows[4][8][30];
    int w = threadIdx.x >> 6, lane = threadIdx.x & 63;
    int a = blockIdx.x * 4 + w;
    if (a >= n_atoms) return;
    int beg, count, count_rd;
    if (col_n) { beg = 0;      count = cnt[a];            count_rd = min(count, MAXD); }
    else       { beg = off[a]; count = off[a + 1] - beg;  count_rd = count; }

    int f = min(lane, 39);
    int u, shi;
    if (f < 8)       { u = f;                 shi = 0; }
    else if (f < 20) { u = 8 + (f - 8) / 3;   shi = 1 + (f - 8) % 3; }
    else             { u = 12 + (f - 20) / 5; shi = 4 + (f - 20) % 5; }

    int rsub = lane >> 3, csub = lane & 7;   // lane stages row rsub, dwords csub*4..+4
    float val = 0.0f;
    for (int i = 0; i < count_rd; i += 8) {
        int nr = min(8, count_rd - i);
        int j = i + rsub;
        bool ok = (j < count_rd);
        size_t ri = col_n ? ((size_t)j * col_n + a) : (size_t)(beg + j);
        if (csub < 7) {   // 28 dwords per row
            float4 v = ok ? *(const float4*)(erow + ri * erow_st + csub * 4)
                          : float4{0.0f, 0.0f, 0.0f, 0.0f};
            *(float2*)&s_rows[w][rsub][csub * 4]     = float2{v.x, v.y};
            *(float2*)&s_rows[w][rsub][csub * 4 + 2] = float2{v.z, v.w};
        }
        // wave-private LDS slice: compiler waitcnt suffices, no barrier
#pragma unroll
        for (int jj = 0; jj < 8; ++jj) {
            float prod = s_rows[w][jj][u] * s_rows[w][jj][16 + shi];
            val += (jj < nr) ? prod : 0.0f;
        }
    }
    if (lane < 40) {
        float c = (float)max(count, 1);
        out[(size_t)a * 40 + lane] = val / c;
    }
}

static inline size_t align256(size_t x) { return (x + 255) & ~(size_t)255; }

extern "C" void kernel_launch(void* const* d_in, const int* in_sizes, int n_in,
                              void* d_out, int out_size, void* d_ws, size_t ws_size,
                              hipStream_t stream)
{
    const float* pos         = (const float*)d_in[0];
    const float* edge_shifts = (const float*)d_in[1];
    const float* cell        = (const float*)d_in[2];
    const float* atom_table  = (const float*)d_in[3];
    const float* fw1 = (const float*)d_in[4];
    const float* fb1 = (const float*)d_in[5];
    const float* fw2 = (const float*)d_in[6];
    const float* fb2 = (const float*)d_in[7];
    const float* fw3 = (const float*)d_in[8];
    const float* fb3 = (const float*)d_in[9];
    const float* gw1 = (const float*)d_in[10];
    const float* gb1 = (const float*)d_in[11];
    const float* gw2 = (const float*)d_in[12];
    const float* gb2 = (const float*)d_in[13];
    const float* gw3 = (const float*)d_in[14];
    const float* gb3 = (const float*)d_in[15];
    const float* gw4 = (const float*)d_in[16];
    const float* gb4 = (const float*)d_in[17];
    const int* A        = (const int*)d_in[18];
    const int* batch    = (const int*)d_in[19];
    const int* edge_src = (const int*)d_in[20];
    const int* edge_dst = (const int*)d_in[21];

    int n_atoms = in_sizes[18];
    int n_edges = in_sizes[20];
    int n_types = in_sizes[3] / 16;   // atom_table rows (EMB=16); spec: 10

    char* w = (char*)d_ws;
    float* Ai10 = (float*)w;                    w += align256((size_t)MAXT * 8 * 4);
    int* cnt_i = (int*)w;                       w += align256((size_t)n_atoms * 4);
    int* off = (int*)w;                         w += align256((size_t)(n_atoms + 1) * 4);
    int* rank0 = (int*)w;                       w += align256((size_t)n_edges * 4);
    unsigned short* W4pk = (unsigned short*)w;  w += align256((size_t)65536 * 2);
    unsigned short* gw1Tp = (unsigned short*)w; w += align256((size_t)2048 * 2);
    unsigned short* gw2T = (unsigned short*)w;  w += align256((size_t)4096 * 2);
    unsigned short* gw3T = (unsigned short*)w;  w += align256((size_t)4096 * 2);
    unsigned short* gb4T2 = (unsigned short*)w; w += align256((size_t)1024 * 2);
    float* erow = (float*)w;                    // last: variable size

    float* out = (float*)d_out;

    // Path selection by workspace size (r13/r14-proven): col-major needs
    // n_atoms*MAXD*EROWC floats; fallback = CSR path (memset+histo+scan).
    size_t used = (size_t)((char*)erow - (char*)d_ws);
    size_t need_col = (size_t)n_atoms * MAXD * EROWC * 4;
    int col_n = 0, erow_st = EROW;
    if (ws_size >= used + need_col) { col_n = n_atoms; erow_st = EROWC; }

    int e_blk = (n_edges + 255) / 256;
    int z_blk = (n_atoms + 255) / 256;

    if (col_n) {
        // 3 nodes: setup(prep+MLP+zero) -> edge(cursor) -> gather
        setup_kernel<<<301 + z_blk, 256, 0, stream>>>(
            gw4, gb4, gw1, gw2, gw3, W4pk, gw1Tp, gw2T, gw3T, gb4T2,
            atom_table, n_types, fw1, fb1, fw2, fb2, fw3, fb3, Ai10,
            edge_dst, cnt_i, rank0, n_edges, n_atoms, /*do_zero=*/1);
    } else {
        hipMemsetAsync(cnt_i, 0, sizeof(int) * (size_t)n_atoms, stream);
        setup_kernel<<<301 + e_blk, 256, 0, stream>>>(
            gw4, gb4, gw1, gw2, gw3, W4pk, gw1Tp, gw2T, gw3T, gb4T2,
            atom_table, n_types, fw1, fb1, fw2, fb2, fw3, fb3, Ai10,
            edge_dst, cnt_i, rank0, n_edges, n_atoms, /*do_zero=*/0);
        scan_kernel<<<1, 1024, 0, stream>>>(cnt_i, off, n_atoms);
    }

    edge_fused<<<(n_edges + 63) / 64, 64, 0, stream>>>(
        pos, edge_shifts, cell, batch, edge_src, edge_dst, A, Ai10,
        gb1, gb2, gb3, gw1Tp, gw2T, gw3T, W4pk, gb4T2, off, rank0,
        cnt_i, erow, n_edges, col_n, erow_st);

    gather_kernel<<<(n_atoms + 3) / 4, 256, 0, stream>>>(
        off, cnt_i, erow, out, n_atoms, col_n, erow_st);
}